// Round 5
// baseline (183.363 us; speedup 1.0000x reference)
//
#include <hip/hip_runtime.h>
#include <math.h>

// ForceMatchingLoss — R5: A (scores->ws) unchanged; jac split 4-way per batch
// (quadrants h x e2, grid 1024, 31KB LDS, 4 blocks/CU), staggered tile order,
// same-XCD placement per batch, P fragments read from ws global.
// agg_jac = SCALE * ( V^T diag(w) K - Out^T Kbar ), w_s = sum_q p_qs.

namespace {
constexpr int Bn = 256, Qn = 16, Sn = 512, Mn = 8, Dn = 128;
constexpr int NT = 512;
constexpr float SCALE = 0.08838834764831845f;  // 1/sqrt(128)
constexpr float CLIPV = 50.0f;

// ---- ws layout ----
// P    bf16 [256][16][512]  @ byte 0        (4,194,304)
// W    f32  [256][512]      @ f32 1048576
// PCG  bf16 [256][16][8]    @ byte 4718592
// WC   f32  [256][8]        @ f32 1196032
// PART f32  [256][4]        @ f32 1198080
constexpr int W_OFF_F = 1048576;
constexpr int PCG_OFF_B = 4718592;
constexpr int WC_OFF_F = 1196032;
constexpr int PART_OFF_F = 1198080;

typedef __attribute__((ext_vector_type(8))) short bf16x8;
typedef __attribute__((ext_vector_type(4))) float f32x4;
#define MFMA16(a, b, c) __builtin_amdgcn_mfma_f32_16x16x32_bf16((a), (b), (c), 0, 0, 0)

__device__ inline unsigned int pack2t(float a, float b) {  // truncating pack, 1 v_perm
  return __builtin_amdgcn_perm(__builtin_bit_cast(unsigned int, b),
                               __builtin_bit_cast(unsigned int, a), 0x07060302u);
}
__device__ inline uint4 pack8(const float* x) {
  return make_uint4(pack2t(x[0], x[1]), pack2t(x[2], x[3]),
                    pack2t(x[4], x[5]), pack2t(x[6], x[7]));
}
__device__ inline unsigned short f2bf(float x) {  // RNE
  unsigned int u = __builtin_bit_cast(unsigned int, x);
  u += 0x7fffu + ((u >> 16) & 1u);
  return (unsigned short)(u >> 16);
}
__device__ inline float bf2f(unsigned short h) {
  unsigned int u = ((unsigned int)h) << 16;
  return __builtin_bit_cast(float, u);
}
union Frag {
  bf16x8 v;
  unsigned int u[4];
  unsigned short h[8];
};

// =====================  Kernel A (unchanged from R4)  =====================
constexpr int A_QS = 0, A_PB = 4352, A_RDM = 20992, A_RDS = 21504,
              A_CGS = 22016, A_CGP = 22528, A_LDSZ = 22784;

__global__ __launch_bounds__(NT) void scores_kernel(
    const float* __restrict__ Qg, const float* __restrict__ Kg,
    const float* __restrict__ Kcg, float* __restrict__ ws) {
  __shared__ __align__(16) char L[A_LDSZ];
  const int b = blockIdx.x, t = threadIdx.x;
  const int lane = t & 63, wv = t >> 6, quad = lane >> 4, l16 = lane & 15;
  const float* Qb = Qg + (size_t)b * Qn * Dn;
  const float* Kb = Kg + (size_t)b * Sn * Dn;
  const float* Kc = Kcg + (size_t)b * Mn * Dn;

  if (t == 0)
    *(float4*)(ws + PART_OFF_F + b * 4) = make_float4(0.f, 0.f, 0.f, 0.f);

  {
    int row = t >> 5, c4 = t & 31;
    float4 qv = ((const float4*)Qb)[t];
    unsigned int p0 = pack2t(qv.x * SCALE, qv.y * SCALE);
    unsigned int p1 = pack2t(qv.z * SCALE, qv.w * SCALE);
    *(unsigned long long*)(L + A_QS + row * 272 + c4 * 8) =
        (unsigned long long)p0 | ((unsigned long long)p1 << 32);
  }
  __syncthreads();

  bf16x8 aq[4];
#pragma unroll
  for (int kk = 0; kk < 4; ++kk)
    aq[kk] = *(const bf16x8*)(L + A_QS + l16 * 272 + kk * 64 + quad * 16);
  f32x4 acc[4];
#pragma unroll
  for (int j = 0; j < 4; ++j) {
    const float* kp = Kb + (size_t)(64 * wv + 16 * j + l16) * Dn + quad * 8;
    f32x4 a = {0.f, 0.f, 0.f, 0.f};
#pragma unroll
    for (int kk = 0; kk < 4; ++kk) {
      float4 lo = *(const float4*)(kp + kk * 32);
      float4 hi = *(const float4*)(kp + kk * 32 + 4);
      Frag f;
      f.u[0] = pack2t(lo.x, lo.y);
      f.u[1] = pack2t(lo.z, lo.w);
      f.u[2] = pack2t(hi.x, hi.y);
      f.u[3] = pack2t(hi.z, hi.w);
      a = MFMA16(aq[kk], f.v, a);
    }
    acc[j] = a;
  }
  {
    float pm[4];
#pragma unroll
    for (int r = 0; r < 4; ++r)
      pm[r] = fmaxf(fmaxf(acc[0][r], acc[1][r]), fmaxf(acc[2][r], acc[3][r]));
#pragma unroll
    for (int o = 1; o < 16; o <<= 1)
#pragma unroll
      for (int r = 0; r < 4; ++r) pm[r] = fmaxf(pm[r], __shfl_xor(pm[r], o));
    if (l16 == 0)
#pragma unroll
      for (int r = 0; r < 4; ++r) *(float*)(L + A_RDM + (quad * 4 + r) * 32 + wv * 4) = pm[r];
  }
  __syncthreads();
  float gm[4];
#pragma unroll
  for (int r = 0; r < 4; ++r) {
    const float* p = (const float*)(L + A_RDM + (quad * 4 + r) * 32);
    float m = p[0];
#pragma unroll
    for (int w = 1; w < 8; ++w) m = fmaxf(m, p[w]);
    gm[r] = m;
  }
  float e[4][4];
  {
    float ps[4] = {0.f, 0.f, 0.f, 0.f};
#pragma unroll
    for (int j = 0; j < 4; ++j)
#pragma unroll
      for (int r = 0; r < 4; ++r) {
        e[j][r] = __expf(acc[j][r] - gm[r]);
        ps[r] += e[j][r];
      }
#pragma unroll
    for (int o = 1; o < 16; o <<= 1)
#pragma unroll
      for (int r = 0; r < 4; ++r) ps[r] += __shfl_xor(ps[r], o);
    if (l16 == 0)
#pragma unroll
      for (int r = 0; r < 4; ++r) *(float*)(L + A_RDS + (quad * 4 + r) * 32 + wv * 4) = ps[r];
  }
  __syncthreads();
  float inv[4];
#pragma unroll
  for (int r = 0; r < 4; ++r) {
    const float* p = (const float*)(L + A_RDS + (quad * 4 + r) * 32);
    float s = 0.f;
#pragma unroll
    for (int w = 0; w < 8; ++w) s += p[w];
    inv[r] = 1.f / s;
  }
#pragma unroll
  for (int j = 0; j < 4; ++j)
#pragma unroll
    for (int r = 0; r < 4; ++r)
      *(unsigned short*)(L + A_PB + (quad * 4 + r) * 1040 + (64 * wv + 16 * j + l16) * 2) =
          f2bf(e[j][r] * inv[r]);
  __syncthreads();
  {
    float wsum = 0.f;
#pragma unroll
    for (int q = 0; q < Qn; ++q)
      wsum += bf2f(*(const unsigned short*)(L + A_PB + q * 1040 + t * 2));
    ws[W_OFF_F + b * 512 + t] = wsum;
  }
#pragma unroll
  for (int i = 0; i < 2; ++i) {
    int idx = t + i * 512, q = idx >> 6, c = idx & 63;
    *(uint4*)((char*)ws + (size_t)b * 16384 + q * 1024 + c * 16) =
        *(const uint4*)(L + A_PB + q * 1040 + c * 16);
  }
  if (wv == 0) {
    const float* kp = Kc + (size_t)(l16 & 7) * Dn + quad * 8;
    f32x4 a = {0.f, 0.f, 0.f, 0.f};
#pragma unroll
    for (int kk = 0; kk < 4; ++kk) {
      float4 lo = *(const float4*)(kp + kk * 32);
      float4 hi = *(const float4*)(kp + kk * 32 + 4);
      Frag f;
      f.u[0] = pack2t(lo.x, lo.y);
      f.u[1] = pack2t(lo.z, lo.w);
      f.u[2] = pack2t(hi.x, hi.y);
      f.u[3] = pack2t(hi.z, hi.w);
      a = MFMA16(aq[kk], f.v, a);
    }
    if (l16 < 8)
#pragma unroll
      for (int r = 0; r < 4; ++r)
        *(float*)(L + A_CGS + (quad * 4 + r) * 32 + l16 * 4) = a[r];
  }
  __syncthreads();
  if (t < 16) {
    float xs[8];
    float m = -1e30f;
#pragma unroll
    for (int s = 0; s < 8; ++s) {
      xs[s] = *(const float*)(L + A_CGS + t * 32 + s * 4);
      m = fmaxf(m, xs[s]);
    }
    float ssum = 0.f;
#pragma unroll
    for (int s = 0; s < 8; ++s) {
      xs[s] = __expf(xs[s] - m);
      ssum += xs[s];
    }
    float iv = 1.f / ssum;
    uint4 pk = make_uint4(pack2t(xs[0] * iv, xs[1] * iv), pack2t(xs[2] * iv, xs[3] * iv),
                          pack2t(xs[4] * iv, xs[5] * iv), pack2t(xs[6] * iv, xs[7] * iv));
    *(uint4*)(L + A_CGP + t * 16) = pk;
    *(uint4*)((char*)ws + PCG_OFF_B + b * 256 + t * 16) = pk;
  }
  __syncthreads();
  if (t < 8) {
    float s = 0.f;
#pragma unroll
    for (int q = 0; q < Qn; ++q)
      s += bf2f(*(const unsigned short*)(L + A_CGP + q * 16 + t * 2));
    ws[WC_OFF_F + b * 8 + t] = s;
  }
}

// =====================  Kernel B: quadrant jac  =====================
// LDS: KT bf16[64][72] @0 | VT @9216 | VTW @18432 | W f32[512] @27648
//      PCG @29696 (16x80) | WC @30976 | RED @31008 -> 31136
constexpr int B_KT = 0, B_VT = 9216, B_VTW = 18432, B_W = 27648,
              B_PCG = 29696, B_WC = 30976, B_RED = 31008, B_LDSZ = 31136;

__global__ __launch_bounds__(NT, 8) void jac_kernel(
    const float* __restrict__ Kg, const float* __restrict__ Vg,
    const float* __restrict__ Kcg, const float* __restrict__ Vcg,
    float* __restrict__ ws) {
  __shared__ __align__(16) char L[B_LDSZ];
  const int g = blockIdx.x;
  const int b = (g & 7) | ((g >> 5) << 3);  // 4 quadrant-blocks of b share an XCD
  const int r4 = (g >> 3) & 3;
  const int h = r4 >> 1, e2 = r4 & 1;       // V-half (C rows), K-half (C cols)
  const int stag = r4 * 2;                  // decorrelate tile phases
  const int t = threadIdx.x, lane = t & 63, wv = t >> 6;
  const int quad = lane >> 4, l16 = lane & 15;

  const float* Kb = Kg + (size_t)b * Sn * Dn;
  const float* Vb = Vg + (size_t)b * Sn * Dn;
  const float* Kc = Kcg + (size_t)b * Mn * Dn;
  const float* Vc = Vcg + (size_t)b * Mn * Dn;
  float* Wl = (float*)(L + B_W);

  // staging: thread owns 8 consecutive s (octet oc) for one local dim dL
  const int dL = t & 63, oc = t >> 6;
  const float* Kcol = Kb + e2 * 64 + dL;
  const float* Vcol = Vb + h * 64 + dL;
  float kpf[8], vpf[8];
  auto load_tiles = [&](int st) {
    int s0 = st * 64 + oc * 8;
#pragma unroll
    for (int i = 0; i < 8; ++i) {
      kpf[i] = Kcol[(size_t)(s0 + i) * Dn];
      vpf[i] = Vcol[(size_t)(s0 + i) * Dn];
    }
  };
  auto store_tiles = [&](int st) {
    int s0 = st * 64 + oc * 8;
    *(uint4*)(L + B_KT + dL * 144 + oc * 16) = pack8(kpf);
    *(uint4*)(L + B_VT + dL * 144 + oc * 16) = pack8(vpf);
    float wvp[8];
#pragma unroll
    for (int i = 0; i < 8; ++i) wvp[i] = Wl[s0 + i] * vpf[i];
    *(uint4*)(L + B_VTW + dL * 144 + oc * 16) = pack8(wvp);
  };

  // preamble: W, PCG, WC from ws; prefetch first tile
  Wl[t] = ws[W_OFF_F + b * 512 + t];
  if (t < 16) {
    *(uint4*)(L + B_PCG + t * 80) = *(const uint4*)((const char*)ws + PCG_OFF_B + b * 256 + t * 16);
    *(uint4*)(L + B_PCG + t * 80 + 16) = make_uint4(0, 0, 0, 0);
    *(uint4*)(L + B_PCG + t * 80 + 32) = make_uint4(0, 0, 0, 0);
    *(uint4*)(L + B_PCG + t * 80 + 48) = make_uint4(0, 0, 0, 0);
  }
  if (t < 8) *(float*)(L + B_WC + t * 4) = ws[WC_OFF_F + b * 8 + t];
  load_tiles(stag);
  __syncthreads();

  // per-wave roles: C tile rows rp*16, cols ch*32; aux = kbar(e) for wv<4, out(d) for wv>=4
  const int rp = wv & 3, ch = wv >> 2;
  const int auxRow = (wv & 3) * 16 + l16;
  const char* auxBase = L + (wv < 4 ? B_KT : B_VT) + auxRow * 144;
  f32x4 Ca = {0.f, 0.f, 0.f, 0.f}, Cb = {0.f, 0.f, 0.f, 0.f}, aux = {0.f, 0.f, 0.f, 0.f};
  const char* Arow = L + B_VTW + (rp * 16 + l16) * 144;
  const char* Brow0 = L + B_KT + (ch * 32 + l16) * 144;
  const char* Brow1 = Brow0 + 16 * 144;
  const char* Pbase = (const char*)ws + (size_t)b * 16384 + l16 * 1024 + quad * 16;

  for (int it = 0; it < 8; ++it) {
    int st = (it + stag) & 7;
    if (it) __syncthreads();
    store_tiles(st);
    __syncthreads();
    if (it < 7) load_tiles((it + 1 + stag) & 7);
    bf16x8 p0 = *(const bf16x8*)(Pbase + st * 128);
    bf16x8 p1 = *(const bf16x8*)(Pbase + st * 128 + 64);
#pragma unroll
    for (int z = 0; z < 2; ++z) {
      int cB = z * 64 + quad * 16;
      bf16x8 fx = *(const bf16x8*)(auxBase + cB);
      aux = MFMA16(z ? p1 : p0, fx, aux);
      bf16x8 A0 = *(const bf16x8*)(Arow + cB);
      bf16x8 B0 = *(const bf16x8*)(Brow0 + cB);
      bf16x8 B1 = *(const bf16x8*)(Brow1 + cB);
      Ca = MFMA16(A0, B0, Ca);
      Cb = MFMA16(A0, B1, Cb);
    }
  }
  __syncthreads();

  // pseudo k-step: C -= Out^T · Kbar (A=-out in VTW, B=kbar in KT, k=q 0..15, pad to 32)
  {
    char* tgt = (char*)(L + (wv < 4 ? B_KT : B_VTW) + auxRow * 144);
    float sgn = (wv < 4) ? 1.f : -1.f;
#pragma unroll
    for (int r = 0; r < 4; ++r)
      *(unsigned short*)(tgt + (quad * 4 + r) * 2) = f2bf(sgn * aux[r]);
  }
  if (t < 128) {
    *(uint4*)(L + B_KT + (t >> 1) * 144 + 32 + (t & 1) * 16) = make_uint4(0, 0, 0, 0);
  } else if (t < 256) {
    int i = t - 128;
    *(uint4*)(L + B_VTW + (i >> 1) * 144 + 32 + (i & 1) * 16) = make_uint4(0, 0, 0, 0);
  }
  __syncthreads();
  {
    int cB = quad * 16;
    bf16x8 A0 = *(const bf16x8*)(Arow + cB);
    bf16x8 B0 = *(const bf16x8*)(Brow0 + cB);
    bf16x8 B1 = *(const bf16x8*)(Brow1 + cB);
    Ca = MFMA16(A0, B0, Ca);
    Cb = MFMA16(A0, B1, Cb);
  }
#pragma unroll
  for (int r = 0; r < 4; ++r) {
    Ca[r] = fminf(fmaxf(SCALE * Ca[r], -CLIPV), CLIPV);
    Cb[r] = fminf(fmaxf(SCALE * Cb[r], -CLIPV), CLIPV);
  }
  __syncthreads();  // arena free for CG

  // ---- CG quadrant: stage K/V halves transposed, cols 8..31 zero ----
  if (t < 64) {
    float kv[8];
#pragma unroll
    for (int i = 0; i < 8; ++i) kv[i] = Kc[(size_t)i * Dn + e2 * 64 + t];
    *(uint4*)(L + B_KT + t * 144) = pack8(kv);
    *(uint4*)(L + B_KT + t * 144 + 16) = make_uint4(0, 0, 0, 0);
    *(uint4*)(L + B_KT + t * 144 + 32) = make_uint4(0, 0, 0, 0);
    *(uint4*)(L + B_KT + t * 144 + 48) = make_uint4(0, 0, 0, 0);
  } else if (t < 128) {
    int d = t - 64;
    float v2[8];
#pragma unroll
    for (int i = 0; i < 8; ++i) v2[i] = Vc[(size_t)i * Dn + h * 64 + d];
    *(uint4*)(L + B_VT + d * 144) = pack8(v2);
    *(uint4*)(L + B_VT + d * 144 + 16) = make_uint4(0, 0, 0, 0);
    *(uint4*)(L + B_VT + d * 144 + 32) = make_uint4(0, 0, 0, 0);
    *(uint4*)(L + B_VT + d * 144 + 48) = make_uint4(0, 0, 0, 0);
  } else if (t < 192) {
    int d = t - 128;
    float wvp[8];
#pragma unroll
    for (int i = 0; i < 8; ++i)
      wvp[i] = Vc[(size_t)i * Dn + h * 64 + d] * *(const float*)(L + B_WC + i * 4);
    *(uint4*)(L + B_VTW + d * 144) = pack8(wvp);
    *(uint4*)(L + B_VTW + d * 144 + 16) = make_uint4(0, 0, 0, 0);
    *(uint4*)(L + B_VTW + d * 144 + 32) = make_uint4(0, 0, 0, 0);
    *(uint4*)(L + B_VTW + d * 144 + 48) = make_uint4(0, 0, 0, 0);
  }
  __syncthreads();
  f32x4 Da = {0.f, 0.f, 0.f, 0.f}, Db = {0.f, 0.f, 0.f, 0.f}, auxc = {0.f, 0.f, 0.f, 0.f};
  {
    int cB = quad * 16;
    bf16x8 pc = *(const bf16x8*)(L + B_PCG + l16 * 80 + cB);
    bf16x8 fx = *(const bf16x8*)(auxBase + cB);
    auxc = MFMA16(pc, fx, auxc);
    bf16x8 A0 = *(const bf16x8*)(Arow + cB);
    bf16x8 B0 = *(const bf16x8*)(Brow0 + cB);
    bf16x8 B1 = *(const bf16x8*)(Brow1 + cB);
    Da = MFMA16(A0, B0, Da);
    Db = MFMA16(A0, B1, Db);
  }
  __syncthreads();
  {
    char* tgt = (char*)(L + (wv < 4 ? B_KT : B_VTW) + auxRow * 144);
    float sgn = (wv < 4) ? 1.f : -1.f;
#pragma unroll
    for (int r = 0; r < 4; ++r)
      *(unsigned short*)(tgt + (quad * 4 + r) * 2) = f2bf(sgn * auxc[r]);
  }
  __syncthreads();
  {
    int cB = quad * 16;
    bf16x8 A0 = *(const bf16x8*)(Arow + cB);
    bf16x8 B0 = *(const bf16x8*)(Brow0 + cB);
    bf16x8 B1 = *(const bf16x8*)(Brow1 + cB);
    Da = MFMA16(A0, B0, Da);
    Db = MFMA16(A0, B1, Db);
  }
#pragma unroll
  for (int r = 0; r < 4; ++r) {
    Da[r] = fminf(fmaxf(SCALE * Da[r], -CLIPV), CLIPV);
    Db[r] = fminf(fmaxf(SCALE * Db[r], -CLIPV), CLIPV);
  }

  // ---- loss partials ----
  float dot = 0.f, nd2 = 0.f, nc2 = 0.f, cons = 0.f;
#pragma unroll
  for (int r = 0; r < 4; ++r) {
    dot += Ca[r] * Da[r] + Cb[r] * Db[r];
    nd2 += Ca[r] * Ca[r] + Cb[r] * Cb[r];
    nc2 += Da[r] * Da[r] + Db[r] * Db[r];
  }
  if (wv >= 4 && e2 == 0) {  // aux/auxc are out_dense/out_cg for this h-half
#pragma unroll
    for (int r = 0; r < 4; ++r) {
      float df = aux[r] - auxc[r];
      cons += df * df;
    }
  }
#pragma unroll
  for (int o = 32; o; o >>= 1) {
    dot += __shfl_xor(dot, o);
    nd2 += __shfl_xor(nd2, o);
    nc2 += __shfl_xor(nc2, o);
    cons += __shfl_xor(cons, o);
  }
  if (lane == 0) {
    float* red = (float*)(L + B_RED);
    red[wv * 4 + 0] = dot;
    red[wv * 4 + 1] = nd2;
    red[wv * 4 + 2] = nc2;
    red[wv * 4 + 3] = cons;
  }
  __syncthreads();
  if (t == 0) {
    const float* red = (const float*)(L + B_RED);
    float d_ = 0.f, n1 = 0.f, n2 = 0.f, cs = 0.f;
#pragma unroll
    for (int w = 0; w < 8; ++w) {
      d_ += red[w * 4 + 0];
      n1 += red[w * 4 + 1];
      n2 += red[w * 4 + 2];
      cs += red[w * 4 + 3];
    }
    atomicAdd(ws + PART_OFF_F + b * 4 + 0, d_);
    atomicAdd(ws + PART_OFF_F + b * 4 + 1, n1);
    atomicAdd(ws + PART_OFF_F + b * 4 + 2, n2);
    atomicAdd(ws + PART_OFF_F + b * 4 + 3, cs);
  }
}

__global__ void finalize_kernel(const float* __restrict__ ws, float* __restrict__ out) {
  __shared__ float sr[256];
  int i = threadIdx.x;
  const float* p = ws + PART_OFF_F + i * 4;
  float cosv = p[0] / (sqrtf(p[1]) * sqrtf(p[2]) + 1e-8f);
  sr[i] = (1.0f - cosv) + p[3] * (1.0f / (float)(Qn * Dn));
  __syncthreads();
  for (int off = 128; off; off >>= 1) {
    if (i < off) sr[i] += sr[i + off];
    __syncthreads();
  }
  if (i == 0) out[0] = sr[0] * (1.0f / (float)Bn);
}
}  // namespace

extern "C" void kernel_launch(void* const* d_in, const int* in_sizes, int n_in,
                              void* d_out, int out_size, void* d_ws, size_t ws_size,
                              hipStream_t stream) {
  const float* q = (const float*)d_in[0];
  const float* k = (const float*)d_in[1];
  const float* v = (const float*)d_in[2];
  const float* kc = (const float*)d_in[3];
  const float* vc = (const float*)d_in[4];
  float* out = (float*)d_out;
  float* ws = (float*)d_ws;
  scores_kernel<<<Bn, NT, 0, stream>>>(q, k, kc, ws);
  jac_kernel<<<4 * Bn, NT, 0, stream>>>(k, v, kc, vc, ws);
  finalize_kernel<<<1, 256, 0, stream>>>(ws, out);
}